// Round 10
// baseline (363.059 us; speedup 1.0000x reference)
//
#include <hip/hip_runtime.h>
#include <hip/hip_bf16.h>

typedef __attribute__((ext_vector_type(8))) short short8;
typedef __attribute__((ext_vector_type(4))) short short4v;
typedef __attribute__((ext_vector_type(4))) float f32x4;

__device__ __forceinline__ float bf2f(unsigned short u) {
    union { unsigned int i; float f; } v; v.i = ((unsigned int)u) << 16; return v.f;
}
__device__ __forceinline__ unsigned short f2bfh(float f) {
    union { __hip_bfloat16 h; unsigned short u; } c;
    c.h = __float2bfloat16(f);
    return c.u;
}

#define GLDS16(g, l) __builtin_amdgcn_global_load_lds( \
    (const __attribute__((address_space(1))) unsigned int*)(g), \
    (__attribute__((address_space(3))) unsigned int*)(l), 16, 0, 0)

// ---------------- f32 -> bf16 conversion kernels ----------------
__global__ __launch_bounds__(256) void cvt_one(
    const float* __restrict__ in, unsigned short* __restrict__ out, int nchunk)
{
    int i = blockIdx.x * 256 + threadIdx.x;
    if (i >= nchunk) return;
    f32x4 a = *(const f32x4*)&in[(size_t)i * 8];
    f32x4 b = *(const f32x4*)&in[(size_t)i * 8 + 4];
    short8 o;
    o[0] = (short)f2bfh(a[0]); o[1] = (short)f2bfh(a[1]);
    o[2] = (short)f2bfh(a[2]); o[3] = (short)f2bfh(a[3]);
    o[4] = (short)f2bfh(b[0]); o[5] = (short)f2bfh(b[1]);
    o[6] = (short)f2bfh(b[2]); o[7] = (short)f2bfh(b[3]);
    *(short8*)&out[(size_t)i * 8] = o;
}

// all 7 weight matrices (each 512x512) in one launch; grid (128, 7)
__global__ __launch_bounds__(256) void cvt_w(
    const float* __restrict__ wq, const float* __restrict__ wk, const float* __restrict__ wv,
    const float* __restrict__ ipw, const float* __restrict__ ow,
    unsigned short* __restrict__ wqb, unsigned short* __restrict__ ipwb,
    unsigned short* __restrict__ owb)
{
    int z = blockIdx.y;
    const float* src;
    unsigned short* dst;
    if (z < 3)      { src = (z == 0 ? wq : z == 1 ? wk : wv); dst = wqb + (size_t)z * 262144; }
    else if (z < 6) { src = ipw + (size_t)(z - 3) * 262144;   dst = ipwb + (size_t)(z - 3) * 262144; }
    else            { src = ow;                                dst = owb; }
    int i = blockIdx.x * 256 + threadIdx.x;
    f32x4 a = *(const f32x4*)&src[(size_t)i * 8];
    f32x4 b = *(const f32x4*)&src[(size_t)i * 8 + 4];
    short8 o;
    o[0] = (short)f2bfh(a[0]); o[1] = (short)f2bfh(a[1]);
    o[2] = (short)f2bfh(a[2]); o[3] = (short)f2bfh(a[3]);
    o[4] = (short)f2bfh(b[0]); o[5] = (short)f2bfh(b[1]);
    o[6] = (short)f2bfh(b[2]); o[7] = (short)f2bfh(b[3]);
    *(short8*)&dst[(size_t)i * 8] = o;
}

// ---------------- RoPE cos/sin tables, TRANSPOSED: [256 i][2048 pos] ----------------
__global__ __launch_bounds__(256) void rope_table(float* __restrict__ ct, float* __restrict__ st)
{
    int i = blockIdx.x;            // 0..255
    const float THC = -0.05190512648261308f;  // -2*log2(10000)/512
    float theta = exp2f(THC * ((float)i - 1.0f));
    for (int k = 0; k < 8; ++k) {
        int pos = k * 256 + threadIdx.x;
        float sn, cs;
        sincosf((float)pos * theta, &sn, &cs);
        ct[i * 2048 + pos] = cs;
        st[i * 2048 + pos] = sn;
    }
}

// ---------------- shared GEMM core (128x128 tile, BK=64, global_load_lds) ----------------
__device__ __forceinline__ void gemm_core(
    const unsigned short* __restrict__ A, int lda,
    const unsigned short* __restrict__ B, int K,
    int rowBase, int colBase, int tid, int lane, int wave,
    short* As, short* Bs, f32x4 (&acc)[4][4])
{
    const int wr = wave >> 1, wc = wave & 1;
    const int lo = lane & 15, hi = lane >> 4;
    for (int k0 = 0; k0 < K; k0 += 64) {
        const unsigned short* Ab = A + (size_t)rowBase * lda + k0;
        const unsigned short* Bb = B + (size_t)colBase * K + k0;
        #pragma unroll
        for (int p = 0; p < 4; ++p) {
            int o = p * 256 + tid;
            GLDS16(&Ab[(size_t)(o >> 3) * lda + (o & 7) * 8], &As[o * 8]);
        }
        #pragma unroll
        for (int p = 0; p < 4; ++p) {
            int o = p * 256 + tid;
            GLDS16(&Bb[(size_t)(o >> 3) * K + (o & 7) * 8], &Bs[o * 8]);
        }
        __syncthreads();
        #pragma unroll
        for (int s = 0; s < 2; ++s) {
            short8 a[4], b[4];
            #pragma unroll
            for (int i = 0; i < 4; ++i)
                a[i] = *(const short8*)&As[(wr * 64 + i * 16 + lo) * 64 + s * 32 + hi * 8];
            #pragma unroll
            for (int j = 0; j < 4; ++j)
                b[j] = *(const short8*)&Bs[(wc * 64 + j * 16 + lo) * 64 + s * 32 + hi * 8];
            #pragma unroll
            for (int i = 0; i < 4; ++i)
                #pragma unroll
                for (int j = 0; j < 4; ++j)
                    acc[i][j] = __builtin_amdgcn_mfma_f32_16x16x32_bf16(a[i], b[j], acc[i][j], 0, 0, 0);
        }
        __syncthreads();
    }
}

// C[M,N] = A[M,K] @ B[N,K]^T (+bias). OUT: 0 = bf16 row-major, 1 = f32 row-major.
template<int HAS_BIAS, int OUT>
__global__ __launch_bounds__(256) void gemm_bt(
    const unsigned short* __restrict__ A, int lda, const unsigned short* __restrict__ B,
    const float* __restrict__ bias, void* __restrict__ Cp,
    int M, int N, int K)
{
    __shared__ __align__(16) short As[128 * 64];
    __shared__ __align__(16) short Bs[128 * 64];
    const int tid = threadIdx.x, lane = tid & 63, wave = tid >> 6;
    const int wr = wave >> 1, wc = wave & 1;
    const int lo = lane & 15, hi = lane >> 4;
    const int rowBase = blockIdx.y * 128;
    const int colBase = blockIdx.x * 128;

    f32x4 acc[4][4] = {};
    gemm_core(A, lda, B, K, rowBase, colBase, tid, lane, wave, As, Bs, acc);

    #pragma unroll
    for (int i = 0; i < 4; ++i) {
        int rowA = rowBase + wr * 64 + i * 16 + hi * 4;
        #pragma unroll
        for (int j = 0; j < 4; ++j) {
            int col = colBase + wc * 64 + j * 16 + lo;
            float bv = HAS_BIAS ? bias[col] : 0.0f;
            #pragma unroll
            for (int r = 0; r < 4; ++r) {
                float v = acc[i][j][r] + bv;
                if (OUT == 1) ((float*)Cp)[(size_t)(rowA + r) * N + col] = v;
                else          ((unsigned short*)Cp)[(size_t)(rowA + r) * N + col] = f2bfh(v);
            }
        }
    }
}

// Stage-1 GEMM with fused RoPE epilogue: T[16384,1536] = rope(x @ [wq;wk;wv]^T).
// Pair (2i, 2i+1) lives in adjacent lanes (col parity == lo parity): partner via shfl_xor(v,1).
__global__ __launch_bounds__(256) void gemm_rope(
    const unsigned short* __restrict__ A, const unsigned short* __restrict__ B,
    unsigned short* __restrict__ T,
    const float* __restrict__ ct, const float* __restrict__ st)
{
    __shared__ __align__(16) short As[128 * 64];
    __shared__ __align__(16) short Bs[128 * 64];
    const int tid = threadIdx.x, lane = tid & 63, wave = tid >> 6;
    const int wr = wave >> 1, wc = wave & 1;
    const int lo = lane & 15, hi = lane >> 4;
    const int rowBase = blockIdx.y * 128;
    const int colBase = blockIdx.x * 128;

    f32x4 acc[4][4] = {};
    gemm_core(A, 512, B, 512, rowBase, colBase, tid, lane, wave, As, Bs, acc);

    const float sgn = (lane & 1) ? -1.0f : 1.0f;
    #pragma unroll
    for (int i = 0; i < 4; ++i) {
        int rowA = rowBase + wr * 64 + i * 16 + hi * 4;
        int pos0 = rowA & 2047;
        #pragma unroll
        for (int j = 0; j < 4; ++j) {
            int col = colBase + wc * 64 + j * 16 + lo;
            int ii = (col & 511) >> 1;
            f32x4 cs = *(const f32x4*)&ct[ii * 2048 + pos0];
            f32x4 sn = *(const f32x4*)&st[ii * 2048 + pos0];
            #pragma unroll
            for (int r = 0; r < 4; ++r) {
                float v = acc[i][j][r];
                float p = __shfl_xor(v, 1);
                // even lane: v*c + p*s ; odd lane: v*c - p*s
                float o = v * cs[r] + sgn * p * sn[r];
                T[(size_t)(rowA + r) * 1536 + col] = f2bfh(o);
            }
        }
    }
}

// Stage-3 grouped in_proj: z=0 -> Qb, z=1 -> Kb (row-major), z=2 -> Vt (transposed layout).
__global__ __launch_bounds__(256) void gemm_inproj(
    const unsigned short* __restrict__ T, const unsigned short* __restrict__ ipwb,
    const float* __restrict__ ipb,
    unsigned short* __restrict__ Qb, unsigned short* __restrict__ Kb,
    unsigned short* __restrict__ Vt)
{
    __shared__ __align__(16) short As[128 * 64];
    __shared__ __align__(16) short Bs[128 * 64];
    const int tid = threadIdx.x, lane = tid & 63, wave = tid >> 6;
    const int wr = wave >> 1, wc = wave & 1;
    const int lo = lane & 15, hi = lane >> 4;
    const int rowBase = blockIdx.y * 128;
    const int colBase = blockIdx.x * 128;
    const int z = blockIdx.z;

    const unsigned short* A = T + z * 512;
    const unsigned short* B = ipwb + (size_t)z * 262144;
    const float* bias = ipb + z * 512;

    f32x4 acc[4][4] = {};
    gemm_core(A, 1536, B, 512, rowBase, colBase, tid, lane, wave, As, Bs, acc);

    unsigned short* Crm = (z == 0) ? Qb : Kb;
    #pragma unroll
    for (int i = 0; i < 4; ++i) {
        int rowA = rowBase + wr * 64 + i * 16 + hi * 4;
        #pragma unroll
        for (int j = 0; j < 4; ++j) {
            int col = colBase + wc * 64 + j * 16 + lo;
            float bv = bias[col];
            if (z == 2) {
                short4v sv;
                #pragma unroll
                for (int r = 0; r < 4; ++r) sv[r] = (short)f2bfh(acc[i][j][r] + bv);
                size_t idx = (((size_t)(rowA >> 11) * 8 + (col >> 6)) * 64 + (col & 63)) * 2048
                             + (rowA & 2047);
                *(short4v*)&Vt[idx] = sv;
            } else {
                #pragma unroll
                for (int r = 0; r < 4; ++r)
                    Crm[(size_t)(rowA + r) * 512 + col] = f2bfh(acc[i][j][r] + bv);
            }
        }
    }
}

// ---------------- causal flash attention ----------------
// Q/K/O: [16384, 512] bf16; Vt: [64 bh][64 d][2048 m] bf16.
// Grid (64 bh, 32 y), qb = 31-y (LPT). Block = one 64-row q-tile, 4 waves x 16 rows.
// K/V + P in XOR-swizzled LDS (stride 64). LDS = 40 KB -> 4 blocks/CU.

__device__ __forceinline__ void attn_step(
    int kt, int NT, int qrow, int lo, int hi,
    const short* __restrict__ KsB, const short* __restrict__ VsB,
    short* __restrict__ Pw,
    short8 (&aq)[2], f32x4 (&o_acc)[4],
    float (&m_i)[4], float (&l_i)[4])
{
    const int swz = (lo & 7) << 3;

    f32x4 sa[4] = {};
    #pragma unroll
    for (int s = 0; s < 2; ++s) {
        short8 bk[4];
        #pragma unroll
        for (int n = 0; n < 4; ++n)
            bk[n] = *(const short8*)&KsB[(n * 16 + lo) * 64 + ((s * 32 + hi * 8) ^ swz)];
        #pragma unroll
        for (int n = 0; n < 4; ++n)
            sa[n] = __builtin_amdgcn_mfma_f32_16x16x32_bf16(aq[s], bk[n], sa[n], 0, 0, 0);
    }

    const bool need_mask = (kt == NT - 1);
    float sv[4][4];
    #pragma unroll
    for (int n = 0; n < 4; ++n) {
        int key = kt * 64 + n * 16 + lo;
        #pragma unroll
        for (int r = 0; r < 4; ++r) {
            float x = sa[n][r];
            if (need_mask) {
                int qr = qrow + hi * 4 + r;
                if (key > qr) x = -1e30f;
            }
            sv[n][r] = x;
        }
    }

    float alpha[4];
    #pragma unroll
    for (int r = 0; r < 4; ++r) {
        float x = fmaxf(fmaxf(sv[0][r], sv[1][r]), fmaxf(sv[2][r], sv[3][r]));
        #pragma unroll
        for (int off = 1; off < 16; off <<= 1) x = fmaxf(x, __shfl_xor(x, off));
        float mn = fmaxf(m_i[r], x);
        alpha[r] = __expf(m_i[r] - mn);
        m_i[r] = mn;
    }
    #pragma unroll
    for (int n = 0; n < 4; ++n)
        #pragma unroll
        for (int r = 0; r < 4; ++r)
            sv[n][r] = __expf(sv[n][r] - m_i[r]);

    #pragma unroll
    for (int r = 0; r < 4; ++r) {
        float x = sv[0][r] + sv[1][r] + sv[2][r] + sv[3][r];
        #pragma unroll
        for (int off = 1; off < 16; off <<= 1) x += __shfl_xor(x, off);
        l_i[r] = l_i[r] * alpha[r] + x;
    }
    #pragma unroll
    for (int t = 0; t < 4; ++t)
        #pragma unroll
        for (int r = 0; r < 4; ++r)
            o_acc[t][r] *= alpha[r];

    #pragma unroll
    for (int n = 0; n < 4; ++n)
        #pragma unroll
        for (int r = 0; r < 4; ++r) {
            int prow = hi * 4 + r;
            Pw[prow * 64 + ((n * 16 + lo) ^ ((prow & 7) << 3))] = (short)f2bfh(sv[n][r]);
        }

    #pragma unroll
    for (int s = 0; s < 2; ++s) {
        short8 ap = *(const short8*)&Pw[lo * 64 + ((s * 32 + hi * 8) ^ swz)];
        #pragma unroll
        for (int t = 0; t < 4; ++t) {
            short8 bv = *(const short8*)&VsB[(t * 16 + lo) * 64 + ((s * 32 + hi * 8) ^ swz)];
            o_acc[t] = __builtin_amdgcn_mfma_f32_16x16x32_bf16(ap, bv, o_acc[t], 0, 0, 0);
        }
    }
}

#define STG_LOAD(kt, KR0, KR1, VR0, VR1) { \
    int rr = tid >> 3, cc = (tid & 7) * 8; \
    KR0 = *(const short8*)&Kp[(rowQ + (size_t)((kt) * 64 + rr)) * 512 + colBase + cc]; \
    KR1 = *(const short8*)&Kp[(rowQ + (size_t)((kt) * 64 + rr + 32)) * 512 + colBase + cc]; \
    VR0 = *(const short8*)&Vh[(size_t)rr * 2048 + (kt) * 64 + cc]; \
    VR1 = *(const short8*)&Vh[(size_t)(rr + 32) * 2048 + (kt) * 64 + cc]; }

#define STG_WRITE(BUF, KR0, KR1, VR0, VR1) { \
    int rr = tid >> 3; \
    int sw = ((tid & 7) * 8) ^ ((rr & 7) << 3); \
    *(short8*)&Ks[BUF][rr * 64 + sw] = KR0; \
    *(short8*)&Ks[BUF][(rr + 32) * 64 + sw] = KR1; \
    *(short8*)&Vs[BUF][rr * 64 + sw] = VR0; \
    *(short8*)&Vs[BUF][(rr + 32) * 64 + sw] = VR1; }

__global__ __launch_bounds__(256, 4) void attn_kernel(
    const unsigned short* __restrict__ Q, const unsigned short* __restrict__ Kp,
    const unsigned short* __restrict__ Vt, unsigned short* __restrict__ O)
{
    const int tid = threadIdx.x, lane = tid & 63, wave = tid >> 6;
    const int lo = lane & 15, hi = lane >> 4;
    const int bh = blockIdx.x;
    const int qb = 31 - blockIdx.y;         // LPT: longest first
    const int bb = bh >> 3, hh = bh & 7;
    const int NT = qb + 1;

    __shared__ __align__(16) short Ks[2][64 * 64];
    __shared__ __align__(16) short Vs[2][64 * 64];
    __shared__ __align__(16) short P[4][16 * 64];
    short* Pw = P[wave];

    const size_t rowQ = (size_t)bb * 2048;
    const int colBase = hh * 64;
    const unsigned short* Vh = Vt + (size_t)bh * 64 * 2048;
    const int qrow = qb * 64 + wave * 16;

    short8 aq[2];
    #pragma unroll
    for (int s = 0; s < 2; ++s) {
        aq[s] = *(const short8*)&Q[(rowQ + qrow + lo) * 512 + colBase + s * 32 + hi * 8];
        #pragma unroll
        for (int e = 0; e < 8; ++e)   // fold softmax scale into Q (0.125 exact in bf16)
            aq[s][e] = (short)f2bfh(bf2f((unsigned short)aq[s][e]) * 0.125f);
    }

    f32x4 o_acc[4] = {};
    float m_i[4], l_i[4];
    #pragma unroll
    for (int r = 0; r < 4; ++r) { m_i[r] = -1e30f; l_i[r] = 0.0f; }

    short8 ka0, ka1, va0, va1;
    short8 kb0, kb1, vb0, vb1;

    STG_LOAD(0, ka0, ka1, va0, va1);
    STG_WRITE(0, ka0, ka1, va0, va1);
    if (1 < NT) STG_LOAD(1, kb0, kb1, vb0, vb1);
    __syncthreads();

    for (int kt = 0; kt < NT; ) {
        if (kt + 1 < NT) STG_WRITE(1, kb0, kb1, vb0, vb1);
        if (kt + 2 < NT) STG_LOAD(kt + 2, ka0, ka1, va0, va1);
        attn_step(kt, NT, qrow, lo, hi, Ks[0], Vs[0], Pw, aq, o_acc, m_i, l_i);
        __syncthreads();
        ++kt;
        if (kt >= NT) break;
        if (kt + 1 < NT) STG_WRITE(0, ka0, ka1, va0, va1);
        if (kt + 2 < NT) STG_LOAD(kt + 2, kb0, kb1, vb0, vb1);
        attn_step(kt, NT, qrow, lo, hi, Ks[1], Vs[1], Pw, aq, o_acc, m_i, l_i);
        __syncthreads();
        ++kt;
    }

    #pragma unroll
    for (int t = 0; t < 4; ++t)
        #pragma unroll
        for (int r = 0; r < 4; ++r) {
            float v = o_acc[t][r] / l_i[r];
            O[(rowQ + qrow + hi * 4 + r) * 512 + colBase + t * 16 + lo] = f2bfh(v);
        }
}

extern "C" void kernel_launch(void* const* d_in, const int* in_sizes, int n_in,
                              void* d_out, int out_size, void* d_ws, size_t ws_size,
                              hipStream_t stream)
{
    (void)in_sizes; (void)n_in; (void)out_size; (void)ws_size;
    const float* x   = (const float*)d_in[0];
    const float* w_q = (const float*)d_in[1];
    const float* w_k = (const float*)d_in[2];
    const float* w_v = (const float*)d_in[3];
    const float* ipw = (const float*)d_in[4];
    const float* ipb = (const float*)d_in[5];
    const float* ow  = (const float*)d_in[6];
    const float* ob  = (const float*)d_in[7];

    const int M = 16384;
    const size_t SZ = (size_t)M * 512;
    // Workspace (~108 MB):
    //   xb [SZ] (reused as Qb) | wqb [3*256K] | ipwb [3*256K] | owb [256K]
    //   T [16384*1536] (first SZ reused as Cb) | Kb [SZ] | Vt [SZ] | ct/st [2*512K f32, [i][pos]]
    unsigned short* xb   = (unsigned short*)d_ws;
    unsigned short* wqb  = xb + SZ;
    unsigned short* ipwb = wqb + 786432;
    unsigned short* owb  = ipwb + 786432;
    unsigned short* T    = owb + 262144;
    unsigned short* Kb   = T + (size_t)M * 1536;
    unsigned short* Vt   = Kb + SZ;               // [64 bh][64 d][2048 m]
    float* ct = (float*)(Vt + SZ);
    float* st = ct + 524288;
    unsigned short* Qb   = xb;
    unsigned short* Cb   = T;

    dim3 blk(256);

    // Stage 0: conversions + rope table
    cvt_one<<<dim3((int)(SZ / 8 / 256)), blk, 0, stream>>>(x, xb, (int)(SZ / 8));
    cvt_w<<<dim3(128, 7), blk, 0, stream>>>(w_q, w_k, w_v, ipw, ow, wqb, ipwb, owb);
    rope_table<<<dim3(256), blk, 0, stream>>>(ct, st);

    // Stage 1+2: T[16384,1536] = rope(xb @ [wq;wk;wv]^T)  (fused epilogue)
    gemm_rope<<<dim3(12, 128), blk, 0, stream>>>(xb, wqb, T, ct, st);

    // Stage 3: grouped in_proj (Q,K row-major; V transposed)
    gemm_inproj<<<dim3(4, 128, 3), blk, 0, stream>>>(T, ipwb, ipb, Qb, Kb, Vt);

    // Stage 4: causal flash attention (LPT, XCD-local per bh, 4 blocks/CU)
    attn_kernel<<<dim3(64, 32), blk, 0, stream>>>(Qb, Kb, Vt, Cb);

    // Stage 5: output projection (f32 out)
    gemm_bt<1, 1><<<dim3(4, 128), blk, 0, stream>>>(Cb, 512, owb, ob, (float*)d_out, M, 512, 512);
}

// Round 11
// 315.986 us; speedup vs baseline: 1.1490x; 1.1490x over previous
//
#include <hip/hip_runtime.h>
#include <hip/hip_bf16.h>

typedef __attribute__((ext_vector_type(8))) short short8;
typedef __attribute__((ext_vector_type(4))) short short4v;
typedef __attribute__((ext_vector_type(4))) float f32x4;

__device__ __forceinline__ float bf2f(unsigned short u) {
    union { unsigned int i; float f; } v; v.i = ((unsigned int)u) << 16; return v.f;
}
__device__ __forceinline__ unsigned short f2bfh(float f) {
    union { __hip_bfloat16 h; unsigned short u; } c;
    c.h = __float2bfloat16(f);
    return c.u;
}

#define GLDS16(g, l) __builtin_amdgcn_global_load_lds( \
    (const __attribute__((address_space(1))) unsigned int*)(g), \
    (__attribute__((address_space(3))) unsigned int*)(l), 16, 0, 0)

// ---------------- f32 -> bf16 conversion kernels ----------------
__global__ __launch_bounds__(256) void cvt_one(
    const float* __restrict__ in, unsigned short* __restrict__ out, int nchunk)
{
    int i = blockIdx.x * 256 + threadIdx.x;
    if (i >= nchunk) return;
    f32x4 a = *(const f32x4*)&in[(size_t)i * 8];
    f32x4 b = *(const f32x4*)&in[(size_t)i * 8 + 4];
    short8 o;
    o[0] = (short)f2bfh(a[0]); o[1] = (short)f2bfh(a[1]);
    o[2] = (short)f2bfh(a[2]); o[3] = (short)f2bfh(a[3]);
    o[4] = (short)f2bfh(b[0]); o[5] = (short)f2bfh(b[1]);
    o[6] = (short)f2bfh(b[2]); o[7] = (short)f2bfh(b[3]);
    *(short8*)&out[(size_t)i * 8] = o;
}

// all 7 weight matrices (each 512x512) in one launch; grid (128, 7)
__global__ __launch_bounds__(256) void cvt_w(
    const float* __restrict__ wq, const float* __restrict__ wk, const float* __restrict__ wv,
    const float* __restrict__ ipw, const float* __restrict__ ow,
    unsigned short* __restrict__ wqb, unsigned short* __restrict__ ipwb,
    unsigned short* __restrict__ owb)
{
    int z = blockIdx.y;
    const float* src;
    unsigned short* dst;
    if (z < 3)      { src = (z == 0 ? wq : z == 1 ? wk : wv); dst = wqb + (size_t)z * 262144; }
    else if (z < 6) { src = ipw + (size_t)(z - 3) * 262144;   dst = ipwb + (size_t)(z - 3) * 262144; }
    else            { src = ow;                                dst = owb; }
    int i = blockIdx.x * 256 + threadIdx.x;
    f32x4 a = *(const f32x4*)&src[(size_t)i * 8];
    f32x4 b = *(const f32x4*)&src[(size_t)i * 8 + 4];
    short8 o;
    o[0] = (short)f2bfh(a[0]); o[1] = (short)f2bfh(a[1]);
    o[2] = (short)f2bfh(a[2]); o[3] = (short)f2bfh(a[3]);
    o[4] = (short)f2bfh(b[0]); o[5] = (short)f2bfh(b[1]);
    o[6] = (short)f2bfh(b[2]); o[7] = (short)f2bfh(b[3]);
    *(short8*)&dst[(size_t)i * 8] = o;
}

// ---------------- RoPE cos/sin tables, TRANSPOSED: [256 i][2048 pos] ----------------
__global__ __launch_bounds__(256) void rope_table(float* __restrict__ ct, float* __restrict__ st)
{
    int i = blockIdx.x;            // 0..255
    const float THC = -0.05190512648261308f;  // -2*log2(10000)/512
    float theta = exp2f(THC * ((float)i - 1.0f));
    for (int k = 0; k < 8; ++k) {
        int pos = k * 256 + threadIdx.x;
        float sn, cs;
        sincosf((float)pos * theta, &sn, &cs);
        ct[i * 2048 + pos] = cs;
        st[i * 2048 + pos] = sn;
    }
}

// ---------------- shared GEMM core (128x128 tile, BK=64, global_load_lds) ----------------
__device__ __forceinline__ void gemm_core(
    const unsigned short* __restrict__ A, int lda,
    const unsigned short* __restrict__ B, int K,
    int rowBase, int colBase, int tid, int lane, int wave,
    short* As, short* Bs, f32x4 (&acc)[4][4])
{
    const int wr = wave >> 1, wc = wave & 1;
    const int lo = lane & 15, hi = lane >> 4;
    for (int k0 = 0; k0 < K; k0 += 64) {
        const unsigned short* Ab = A + (size_t)rowBase * lda + k0;
        const unsigned short* Bb = B + (size_t)colBase * K + k0;
        #pragma unroll
        for (int p = 0; p < 4; ++p) {
            int o = p * 256 + tid;
            GLDS16(&Ab[(size_t)(o >> 3) * lda + (o & 7) * 8], &As[o * 8]);
        }
        #pragma unroll
        for (int p = 0; p < 4; ++p) {
            int o = p * 256 + tid;
            GLDS16(&Bb[(size_t)(o >> 3) * K + (o & 7) * 8], &Bs[o * 8]);
        }
        __syncthreads();
        #pragma unroll
        for (int s = 0; s < 2; ++s) {
            short8 a[4], b[4];
            #pragma unroll
            for (int i = 0; i < 4; ++i)
                a[i] = *(const short8*)&As[(wr * 64 + i * 16 + lo) * 64 + s * 32 + hi * 8];
            #pragma unroll
            for (int j = 0; j < 4; ++j)
                b[j] = *(const short8*)&Bs[(wc * 64 + j * 16 + lo) * 64 + s * 32 + hi * 8];
            #pragma unroll
            for (int i = 0; i < 4; ++i)
                #pragma unroll
                for (int j = 0; j < 4; ++j)
                    acc[i][j] = __builtin_amdgcn_mfma_f32_16x16x32_bf16(a[i], b[j], acc[i][j], 0, 0, 0);
        }
        __syncthreads();
    }
}

// C[M,N] = A[M,K] @ B[N,K]^T (+bias). OUT: 0 = bf16 row-major, 1 = f32 row-major.
template<int HAS_BIAS, int OUT>
__global__ __launch_bounds__(256) void gemm_bt(
    const unsigned short* __restrict__ A, int lda, const unsigned short* __restrict__ B,
    const float* __restrict__ bias, void* __restrict__ Cp,
    int M, int N, int K)
{
    __shared__ __align__(16) short As[128 * 64];
    __shared__ __align__(16) short Bs[128 * 64];
    const int tid = threadIdx.x, lane = tid & 63, wave = tid >> 6;
    const int wr = wave >> 1, wc = wave & 1;
    const int lo = lane & 15, hi = lane >> 4;
    const int rowBase = blockIdx.y * 128;
    const int colBase = blockIdx.x * 128;

    f32x4 acc[4][4] = {};
    gemm_core(A, lda, B, K, rowBase, colBase, tid, lane, wave, As, Bs, acc);

    #pragma unroll
    for (int i = 0; i < 4; ++i) {
        int rowA = rowBase + wr * 64 + i * 16 + hi * 4;
        #pragma unroll
        for (int j = 0; j < 4; ++j) {
            int col = colBase + wc * 64 + j * 16 + lo;
            float bv = HAS_BIAS ? bias[col] : 0.0f;
            #pragma unroll
            for (int r = 0; r < 4; ++r) {
                float v = acc[i][j][r] + bv;
                if (OUT == 1) ((float*)Cp)[(size_t)(rowA + r) * N + col] = v;
                else          ((unsigned short*)Cp)[(size_t)(rowA + r) * N + col] = f2bfh(v);
            }
        }
    }
}

// Stage-1 GEMM with fused RoPE epilogue: T[16384,1536] = rope(x @ [wq;wk;wv]^T).
__global__ __launch_bounds__(256) void gemm_rope(
    const unsigned short* __restrict__ A, const unsigned short* __restrict__ B,
    unsigned short* __restrict__ T,
    const float* __restrict__ ct, const float* __restrict__ st)
{
    __shared__ __align__(16) short As[128 * 64];
    __shared__ __align__(16) short Bs[128 * 64];
    const int tid = threadIdx.x, lane = tid & 63, wave = tid >> 6;
    const int wr = wave >> 1, wc = wave & 1;
    const int lo = lane & 15, hi = lane >> 4;
    const int rowBase = blockIdx.y * 128;
    const int colBase = blockIdx.x * 128;

    f32x4 acc[4][4] = {};
    gemm_core(A, 512, B, 512, rowBase, colBase, tid, lane, wave, As, Bs, acc);

    const float sgn = (lane & 1) ? -1.0f : 1.0f;
    #pragma unroll
    for (int i = 0; i < 4; ++i) {
        int rowA = rowBase + wr * 64 + i * 16 + hi * 4;
        int pos0 = rowA & 2047;
        #pragma unroll
        for (int j = 0; j < 4; ++j) {
            int col = colBase + wc * 64 + j * 16 + lo;
            int ii = (col & 511) >> 1;
            f32x4 cs = *(const f32x4*)&ct[ii * 2048 + pos0];
            f32x4 sn = *(const f32x4*)&st[ii * 2048 + pos0];
            #pragma unroll
            for (int r = 0; r < 4; ++r) {
                float v = acc[i][j][r];
                float p = __shfl_xor(v, 1);
                float o = v * cs[r] + sgn * p * sn[r];
                T[(size_t)(rowA + r) * 1536 + col] = f2bfh(o);
            }
        }
    }
}

// Stage-3 grouped in_proj: z=0 -> Qb, z=1 -> Kb (row-major), z=2 -> Vt (transposed layout).
__global__ __launch_bounds__(256) void gemm_inproj(
    const unsigned short* __restrict__ T, const unsigned short* __restrict__ ipwb,
    const float* __restrict__ ipb,
    unsigned short* __restrict__ Qb, unsigned short* __restrict__ Kb,
    unsigned short* __restrict__ Vt)
{
    __shared__ __align__(16) short As[128 * 64];
    __shared__ __align__(16) short Bs[128 * 64];
    const int tid = threadIdx.x, lane = tid & 63, wave = tid >> 6;
    const int wr = wave >> 1, wc = wave & 1;
    const int lo = lane & 15, hi = lane >> 4;
    const int rowBase = blockIdx.y * 128;
    const int colBase = blockIdx.x * 128;
    const int z = blockIdx.z;

    const unsigned short* A = T + z * 512;
    const unsigned short* B = ipwb + (size_t)z * 262144;
    const float* bias = ipb + z * 512;

    f32x4 acc[4][4] = {};
    gemm_core(A, 1536, B, 512, rowBase, colBase, tid, lane, wave, As, Bs, acc);

    unsigned short* Crm = (z == 0) ? Qb : Kb;
    #pragma unroll
    for (int i = 0; i < 4; ++i) {
        int rowA = rowBase + wr * 64 + i * 16 + hi * 4;
        #pragma unroll
        for (int j = 0; j < 4; ++j) {
            int col = colBase + wc * 64 + j * 16 + lo;
            float bv = bias[col];
            if (z == 2) {
                short4v sv;
                #pragma unroll
                for (int r = 0; r < 4; ++r) sv[r] = (short)f2bfh(acc[i][j][r] + bv);
                size_t idx = (((size_t)(rowA >> 11) * 8 + (col >> 6)) * 64 + (col & 63)) * 2048
                             + (rowA & 2047);
                *(short4v*)&Vt[idx] = sv;
            } else {
                #pragma unroll
                for (int r = 0; r < 4; ++r)
                    Crm[(size_t)(rowA + r) * 512 + col] = f2bfh(acc[i][j][r] + bv);
            }
        }
    }
}

// ---------------- causal flash attention ----------------
// Q/K/O: [16384, 512] bf16; Vt: [64 bh][64 d][2048 m] bf16.
// Grid (64 bh, 32 y), qb = 31-y (LPT). Block = one 64-row q-tile, 4 waves x 16 rows.
// K/V + P XOR-swizzled in LDS (stride 64, 0 conflicts). LDS = 40 KB; VGPR ~72 ->
// runtime residency 4 blocks/CU (launch_bounds(256,3) only caps the allocator; m69:
// 72<=128 VGPR allows 16 waves/CU). l-reduction deferred to epilogue (per-lane partials).

__device__ __forceinline__ void attn_step(
    int kt, int NT, int qrow, int lo, int hi,
    const short* __restrict__ KsB, const short* __restrict__ VsB,
    short* __restrict__ Pw,
    short8 (&aq)[2], f32x4 (&o_acc)[4],
    float (&m_i)[4], float (&l_i)[4])
{
    const int swz = (lo & 7) << 3;

    f32x4 sa[4] = {};
    #pragma unroll
    for (int s = 0; s < 2; ++s) {
        short8 bk[4];
        #pragma unroll
        for (int n = 0; n < 4; ++n)
            bk[n] = *(const short8*)&KsB[(n * 16 + lo) * 64 + ((s * 32 + hi * 8) ^ swz)];
        #pragma unroll
        for (int n = 0; n < 4; ++n)
            sa[n] = __builtin_amdgcn_mfma_f32_16x16x32_bf16(aq[s], bk[n], sa[n], 0, 0, 0);
    }

    const bool need_mask = (kt == NT - 1);
    float sv[4][4];
    #pragma unroll
    for (int n = 0; n < 4; ++n) {
        int key = kt * 64 + n * 16 + lo;
        #pragma unroll
        for (int r = 0; r < 4; ++r) {
            float x = sa[n][r];
            if (need_mask) {
                int qr = qrow + hi * 4 + r;
                if (key > qr) x = -1e30f;
            }
            sv[n][r] = x;
        }
    }

    float alpha[4];
    #pragma unroll
    for (int r = 0; r < 4; ++r) {
        float x = fmaxf(fmaxf(sv[0][r], sv[1][r]), fmaxf(sv[2][r], sv[3][r]));
        #pragma unroll
        for (int off = 1; off < 16; off <<= 1) x = fmaxf(x, __shfl_xor(x, off));
        float mn = fmaxf(m_i[r], x);
        alpha[r] = __expf(m_i[r] - mn);
        m_i[r] = mn;
    }
    #pragma unroll
    for (int n = 0; n < 4; ++n)
        #pragma unroll
        for (int r = 0; r < 4; ++r)
            sv[n][r] = __expf(sv[n][r] - m_i[r]);

    // deferred l: per-lane partial sum only (cross-lane reduce once in epilogue)
    #pragma unroll
    for (int r = 0; r < 4; ++r)
        l_i[r] = l_i[r] * alpha[r] + (sv[0][r] + sv[1][r]) + (sv[2][r] + sv[3][r]);

    #pragma unroll
    for (int t = 0; t < 4; ++t)
        #pragma unroll
        for (int r = 0; r < 4; ++r)
            o_acc[t][r] *= alpha[r];

    #pragma unroll
    for (int n = 0; n < 4; ++n)
        #pragma unroll
        for (int r = 0; r < 4; ++r) {
            int prow = hi * 4 + r;
            Pw[prow * 64 + ((n * 16 + lo) ^ ((prow & 7) << 3))] = (short)f2bfh(sv[n][r]);
        }

    #pragma unroll
    for (int s = 0; s < 2; ++s) {
        short8 ap = *(const short8*)&Pw[lo * 64 + ((s * 32 + hi * 8) ^ swz)];
        #pragma unroll
        for (int t = 0; t < 4; ++t) {
            short8 bv = *(const short8*)&VsB[(t * 16 + lo) * 64 + ((s * 32 + hi * 8) ^ swz)];
            o_acc[t] = __builtin_amdgcn_mfma_f32_16x16x32_bf16(ap, bv, o_acc[t], 0, 0, 0);
        }
    }
}

#define STG_LOAD(kt, KR0, KR1, VR0, VR1) { \
    int rr = tid >> 3, cc = (tid & 7) * 8; \
    KR0 = *(const short8*)&Kp[(rowQ + (size_t)((kt) * 64 + rr)) * 512 + colBase + cc]; \
    KR1 = *(const short8*)&Kp[(rowQ + (size_t)((kt) * 64 + rr + 32)) * 512 + colBase + cc]; \
    VR0 = *(const short8*)&Vh[(size_t)rr * 2048 + (kt) * 64 + cc]; \
    VR1 = *(const short8*)&Vh[(size_t)(rr + 32) * 2048 + (kt) * 64 + cc]; }

#define STG_WRITE(BUF, KR0, KR1, VR0, VR1) { \
    int rr = tid >> 3; \
    int sw = ((tid & 7) * 8) ^ ((rr & 7) << 3); \
    *(short8*)&Ks[BUF][rr * 64 + sw] = KR0; \
    *(short8*)&Ks[BUF][(rr + 32) * 64 + sw] = KR1; \
    *(short8*)&Vs[BUF][rr * 64 + sw] = VR0; \
    *(short8*)&Vs[BUF][(rr + 32) * 64 + sw] = VR1; }

__global__ __launch_bounds__(256, 3) void attn_kernel(
    const unsigned short* __restrict__ Q, const unsigned short* __restrict__ Kp,
    const unsigned short* __restrict__ Vt, unsigned short* __restrict__ O)
{
    const int tid = threadIdx.x, lane = tid & 63, wave = tid >> 6;
    const int lo = lane & 15, hi = lane >> 4;
    const int bh = blockIdx.x;
    const int qb = 31 - blockIdx.y;         // LPT: longest first
    const int bb = bh >> 3, hh = bh & 7;
    const int NT = qb + 1;

    __shared__ __align__(16) short Ks[2][64 * 64];
    __shared__ __align__(16) short Vs[2][64 * 64];
    __shared__ __align__(16) short P[4][16 * 64];
    short* Pw = P[wave];

    const size_t rowQ = (size_t)bb * 2048;
    const int colBase = hh * 64;
    const unsigned short* Vh = Vt + (size_t)bh * 64 * 2048;
    const int qrow = qb * 64 + wave * 16;

    short8 aq[2];
    #pragma unroll
    for (int s = 0; s < 2; ++s) {
        aq[s] = *(const short8*)&Q[(rowQ + qrow + lo) * 512 + colBase + s * 32 + hi * 8];
        #pragma unroll
        for (int e = 0; e < 8; ++e)   // fold softmax scale into Q (0.125 exact in bf16)
            aq[s][e] = (short)f2bfh(bf2f((unsigned short)aq[s][e]) * 0.125f);
    }

    f32x4 o_acc[4] = {};
    float m_i[4], l_i[4];
    #pragma unroll
    for (int r = 0; r < 4; ++r) { m_i[r] = -1e30f; l_i[r] = 0.0f; }

    short8 ka0, ka1, va0, va1;
    short8 kb0, kb1, vb0, vb1;

    STG_LOAD(0, ka0, ka1, va0, va1);
    STG_WRITE(0, ka0, ka1, va0, va1);
    if (1 < NT) STG_LOAD(1, kb0, kb1, vb0, vb1);
    __syncthreads();

    for (int kt = 0; kt < NT; ) {
        if (kt + 1 < NT) STG_WRITE(1, kb0, kb1, vb0, vb1);
        if (kt + 2 < NT) STG_LOAD(kt + 2, ka0, ka1, va0, va1);
        attn_step(kt, NT, qrow, lo, hi, Ks[0], Vs[0], Pw, aq, o_acc, m_i, l_i);
        __syncthreads();
        ++kt;
        if (kt >= NT) break;
        if (kt + 1 < NT) STG_WRITE(0, ka0, ka1, va0, va1);
        if (kt + 2 < NT) STG_LOAD(kt + 2, kb0, kb1, vb0, vb1);
        attn_step(kt, NT, qrow, lo, hi, Ks[1], Vs[1], Pw, aq, o_acc, m_i, l_i);
        __syncthreads();
        ++kt;
    }

    // epilogue: cross-lane l reduction (deferred from the loop)
    #pragma unroll
    for (int r = 0; r < 4; ++r) {
        float x = l_i[r];
        #pragma unroll
        for (int off = 1; off < 16; off <<= 1) x += __shfl_xor(x, off);
        l_i[r] = x;
    }

    #pragma unroll
    for (int t = 0; t < 4; ++t)
        #pragma unroll
        for (int r = 0; r < 4; ++r) {
            float v = o_acc[t][r] / l_i[r];
            O[(rowQ + qrow + hi * 4 + r) * 512 + colBase + t * 16 + lo] = f2bfh(v);
        }
}

extern "C" void kernel_launch(void* const* d_in, const int* in_sizes, int n_in,
                              void* d_out, int out_size, void* d_ws, size_t ws_size,
                              hipStream_t stream)
{
    (void)in_sizes; (void)n_in; (void)out_size; (void)ws_size;
    const float* x   = (const float*)d_in[0];
    const float* w_q = (const float*)d_in[1];
    const float* w_k = (const float*)d_in[2];
    const float* w_v = (const float*)d_in[3];
    const float* ipw = (const float*)d_in[4];
    const float* ipb = (const float*)d_in[5];
    const float* ow  = (const float*)d_in[6];
    const float* ob  = (const float*)d_in[7];

    const int M = 16384;
    const size_t SZ = (size_t)M * 512;
    unsigned short* xb   = (unsigned short*)d_ws;
    unsigned short* wqb  = xb + SZ;
    unsigned short* ipwb = wqb + 786432;
    unsigned short* owb  = ipwb + 786432;
    unsigned short* T    = owb + 262144;
    unsigned short* Kb   = T + (size_t)M * 1536;
    unsigned short* Vt   = Kb + SZ;               // [64 bh][64 d][2048 m]
    float* ct = (float*)(Vt + SZ);
    float* st = ct + 524288;
    unsigned short* Qb   = xb;
    unsigned short* Cb   = T;

    dim3 blk(256);

    // Stage 0: conversions + rope table
    cvt_one<<<dim3((int)(SZ / 8 / 256)), blk, 0, stream>>>(x, xb, (int)(SZ / 8));
    cvt_w<<<dim3(128, 7), blk, 0, stream>>>(w_q, w_k, w_v, ipw, ow, wqb, ipwb, owb);
    rope_table<<<dim3(256), blk, 0, stream>>>(ct, st);

    // Stage 1+2: T[16384,1536] = rope(xb @ [wq;wk;wv]^T)  (fused epilogue)
    gemm_rope<<<dim3(12, 128), blk, 0, stream>>>(xb, wqb, T, ct, st);

    // Stage 3: grouped in_proj (Q,K row-major; V transposed)
    gemm_inproj<<<dim3(4, 128, 3), blk, 0, stream>>>(T, ipwb, ipb, Qb, Kb, Vt);

    // Stage 4: causal flash attention (LPT, XCD-local per bh)
    attn_kernel<<<dim3(64, 32), blk, 0, stream>>>(Qb, Kb, Vt, Cb);

    // Stage 5: output projection (f32 out)
    gemm_bt<1, 1><<<dim3(4, 128), blk, 0, stream>>>(Cb, 512, owb, ob, (float*)d_out, M, 512, 512);
}

// Round 12
// 304.073 us; speedup vs baseline: 1.1940x; 1.0392x over previous
//
#include <hip/hip_runtime.h>
#include <hip/hip_bf16.h>

typedef __attribute__((ext_vector_type(8))) short short8;
typedef __attribute__((ext_vector_type(4))) short short4v;
typedef __attribute__((ext_vector_type(4))) float f32x4;

__device__ __forceinline__ float bf2f(unsigned short u) {
    union { unsigned int i; float f; } v; v.i = ((unsigned int)u) << 16; return v.f;
}
__device__ __forceinline__ unsigned short f2bfh(float f) {
    union { __hip_bfloat16 h; unsigned short u; } c;
    c.h = __float2bfloat16(f);
    return c.u;
}

#define GLDS16(g, l) __builtin_amdgcn_global_load_lds( \
    (const __attribute__((address_space(1))) unsigned int*)(g), \
    (__attribute__((address_space(3))) unsigned int*)(l), 16, 0, 0)

#if __has_builtin(__builtin_amdgcn_mfma_f32_16x16x16_bf16)
#define MFMA_PV(a, b, c) __builtin_amdgcn_mfma_f32_16x16x16_bf16(a, b, c, 0, 0, 0)
#else
#define MFMA_PV(a, b, c) __builtin_amdgcn_mfma_f32_16x16x16bf16_1k(a, b, c, 0, 0, 0)
#endif

// ---------------- f32 -> bf16 conversion kernels ----------------
__global__ __launch_bounds__(256) void cvt_one(
    const float* __restrict__ in, unsigned short* __restrict__ out, int nchunk)
{
    int i = blockIdx.x * 256 + threadIdx.x;
    if (i >= nchunk) return;
    f32x4 a = *(const f32x4*)&in[(size_t)i * 8];
    f32x4 b = *(const f32x4*)&in[(size_t)i * 8 + 4];
    short8 o;
    o[0] = (short)f2bfh(a[0]); o[1] = (short)f2bfh(a[1]);
    o[2] = (short)f2bfh(a[2]); o[3] = (short)f2bfh(a[3]);
    o[4] = (short)f2bfh(b[0]); o[5] = (short)f2bfh(b[1]);
    o[6] = (short)f2bfh(b[2]); o[7] = (short)f2bfh(b[3]);
    *(short8*)&out[(size_t)i * 8] = o;
}

// all 7 weight matrices (each 512x512) in one launch; grid (128, 7)
__global__ __launch_bounds__(256) void cvt_w(
    const float* __restrict__ wq, const float* __restrict__ wk, const float* __restrict__ wv,
    const float* __restrict__ ipw, const float* __restrict__ ow,
    unsigned short* __restrict__ wqb, unsigned short* __restrict__ ipwb,
    unsigned short* __restrict__ owb)
{
    int z = blockIdx.y;
    const float* src;
    unsigned short* dst;
    if (z < 3)      { src = (z == 0 ? wq : z == 1 ? wk : wv); dst = wqb + (size_t)z * 262144; }
    else if (z < 6) { src = ipw + (size_t)(z - 3) * 262144;   dst = ipwb + (size_t)(z - 3) * 262144; }
    else            { src = ow;                                dst = owb; }
    int i = blockIdx.x * 256 + threadIdx.x;
    f32x4 a = *(const f32x4*)&src[(size_t)i * 8];
    f32x4 b = *(const f32x4*)&src[(size_t)i * 8 + 4];
    short8 o;
    o[0] = (short)f2bfh(a[0]); o[1] = (short)f2bfh(a[1]);
    o[2] = (short)f2bfh(a[2]); o[3] = (short)f2bfh(a[3]);
    o[4] = (short)f2bfh(b[0]); o[5] = (short)f2bfh(b[1]);
    o[6] = (short)f2bfh(b[2]); o[7] = (short)f2bfh(b[3]);
    *(short8*)&dst[(size_t)i * 8] = o;
}

// ---------------- RoPE cos/sin tables, TRANSPOSED: [256 i][2048 pos] ----------------
__global__ __launch_bounds__(256) void rope_table(float* __restrict__ ct, float* __restrict__ st)
{
    int i = blockIdx.x;            // 0..255
    const float THC = -0.05190512648261308f;  // -2*log2(10000)/512
    float theta = exp2f(THC * ((float)i - 1.0f));
    for (int k = 0; k < 8; ++k) {
        int pos = k * 256 + threadIdx.x;
        float sn, cs;
        sincosf((float)pos * theta, &sn, &cs);
        ct[i * 2048 + pos] = cs;
        st[i * 2048 + pos] = sn;
    }
}

// ---------------- shared GEMM core (128x128 tile, BK=64, global_load_lds) ----------------
__device__ __forceinline__ void gemm_core(
    const unsigned short* __restrict__ A, int lda,
    const unsigned short* __restrict__ B, int K,
    int rowBase, int colBase, int tid, int lane, int wave,
    short* As, short* Bs, f32x4 (&acc)[4][4])
{
    const int wr = wave >> 1, wc = wave & 1;
    const int lo = lane & 15, hi = lane >> 4;
    for (int k0 = 0; k0 < K; k0 += 64) {
        const unsigned short* Ab = A + (size_t)rowBase * lda + k0;
        const unsigned short* Bb = B + (size_t)colBase * K + k0;
        #pragma unroll
        for (int p = 0; p < 4; ++p) {
            int o = p * 256 + tid;
            GLDS16(&Ab[(size_t)(o >> 3) * lda + (o & 7) * 8], &As[o * 8]);
        }
        #pragma unroll
        for (int p = 0; p < 4; ++p) {
            int o = p * 256 + tid;
            GLDS16(&Bb[(size_t)(o >> 3) * K + (o & 7) * 8], &Bs[o * 8]);
        }
        __syncthreads();
        #pragma unroll
        for (int s = 0; s < 2; ++s) {
            short8 a[4], b[4];
            #pragma unroll
            for (int i = 0; i < 4; ++i)
                a[i] = *(const short8*)&As[(wr * 64 + i * 16 + lo) * 64 + s * 32 + hi * 8];
            #pragma unroll
            for (int j = 0; j < 4; ++j)
                b[j] = *(const short8*)&Bs[(wc * 64 + j * 16 + lo) * 64 + s * 32 + hi * 8];
            #pragma unroll
            for (int i = 0; i < 4; ++i)
                #pragma unroll
                for (int j = 0; j < 4; ++j)
                    acc[i][j] = __builtin_amdgcn_mfma_f32_16x16x32_bf16(a[i], b[j], acc[i][j], 0, 0, 0);
        }
        __syncthreads();
    }
}

// C[M,N] = A[M,K] @ B[N,K]^T (+bias). OUT: 0 = bf16 row-major, 1 = f32 row-major.
template<int HAS_BIAS, int OUT>
__global__ __launch_bounds__(256) void gemm_bt(
    const unsigned short* __restrict__ A, int lda, const unsigned short* __restrict__ B,
    const float* __restrict__ bias, void* __restrict__ Cp,
    int M, int N, int K)
{
    __shared__ __align__(16) short As[128 * 64];
    __shared__ __align__(16) short Bs[128 * 64];
    const int tid = threadIdx.x, lane = tid & 63, wave = tid >> 6;
    const int wr = wave >> 1, wc = wave & 1;
    const int lo = lane & 15, hi = lane >> 4;
    const int rowBase = blockIdx.y * 128;
    const int colBase = blockIdx.x * 128;

    f32x4 acc[4][4] = {};
    gemm_core(A, lda, B, K, rowBase, colBase, tid, lane, wave, As, Bs, acc);

    #pragma unroll
    for (int i = 0; i < 4; ++i) {
        int rowA = rowBase + wr * 64 + i * 16 + hi * 4;
        #pragma unroll
        for (int j = 0; j < 4; ++j) {
            int col = colBase + wc * 64 + j * 16 + lo;
            float bv = HAS_BIAS ? bias[col] : 0.0f;
            #pragma unroll
            for (int r = 0; r < 4; ++r) {
                float v = acc[i][j][r] + bv;
                if (OUT == 1) ((float*)Cp)[(size_t)(rowA + r) * N + col] = v;
                else          ((unsigned short*)Cp)[(size_t)(rowA + r) * N + col] = f2bfh(v);
            }
        }
    }
}

// Stage-1 GEMM with fused RoPE epilogue: T[16384,1536] = rope(x @ [wq;wk;wv]^T).
__global__ __launch_bounds__(256) void gemm_rope(
    const unsigned short* __restrict__ A, const unsigned short* __restrict__ B,
    unsigned short* __restrict__ T,
    const float* __restrict__ ct, const float* __restrict__ st)
{
    __shared__ __align__(16) short As[128 * 64];
    __shared__ __align__(16) short Bs[128 * 64];
    const int tid = threadIdx.x, lane = tid & 63, wave = tid >> 6;
    const int wr = wave >> 1, wc = wave & 1;
    const int lo = lane & 15, hi = lane >> 4;
    const int rowBase = blockIdx.y * 128;
    const int colBase = blockIdx.x * 128;

    f32x4 acc[4][4] = {};
    gemm_core(A, 512, B, 512, rowBase, colBase, tid, lane, wave, As, Bs, acc);

    const float sgn = (lane & 1) ? -1.0f : 1.0f;
    #pragma unroll
    for (int i = 0; i < 4; ++i) {
        int rowA = rowBase + wr * 64 + i * 16 + hi * 4;
        int pos0 = rowA & 2047;
        #pragma unroll
        for (int j = 0; j < 4; ++j) {
            int col = colBase + wc * 64 + j * 16 + lo;
            int ii = (col & 511) >> 1;
            f32x4 cs = *(const f32x4*)&ct[ii * 2048 + pos0];
            f32x4 sn = *(const f32x4*)&st[ii * 2048 + pos0];
            #pragma unroll
            for (int r = 0; r < 4; ++r) {
                float v = acc[i][j][r];
                float p = __shfl_xor(v, 1);
                float o = v * cs[r] + sgn * p * sn[r];
                T[(size_t)(rowA + r) * 1536 + col] = f2bfh(o);
            }
        }
    }
}

// Stage-3 grouped in_proj: z=0 -> Qb, z=1 -> Kb (row-major), z=2 -> Vt (transposed layout).
__global__ __launch_bounds__(256) void gemm_inproj(
    const unsigned short* __restrict__ T, const unsigned short* __restrict__ ipwb,
    const float* __restrict__ ipb,
    unsigned short* __restrict__ Qb, unsigned short* __restrict__ Kb,
    unsigned short* __restrict__ Vt)
{
    __shared__ __align__(16) short As[128 * 64];
    __shared__ __align__(16) short Bs[128 * 64];
    const int tid = threadIdx.x, lane = tid & 63, wave = tid >> 6;
    const int wr = wave >> 1, wc = wave & 1;
    const int lo = lane & 15, hi = lane >> 4;
    const int rowBase = blockIdx.y * 128;
    const int colBase = blockIdx.x * 128;
    const int z = blockIdx.z;

    const unsigned short* A = T + z * 512;
    const unsigned short* B = ipwb + (size_t)z * 262144;
    const float* bias = ipb + z * 512;

    f32x4 acc[4][4] = {};
    gemm_core(A, 1536, B, 512, rowBase, colBase, tid, lane, wave, As, Bs, acc);

    unsigned short* Crm = (z == 0) ? Qb : Kb;
    #pragma unroll
    for (int i = 0; i < 4; ++i) {
        int rowA = rowBase + wr * 64 + i * 16 + hi * 4;
        #pragma unroll
        for (int j = 0; j < 4; ++j) {
            int col = colBase + wc * 64 + j * 16 + lo;
            float bv = bias[col];
            if (z == 2) {
                short4v sv;
                #pragma unroll
                for (int r = 0; r < 4; ++r) sv[r] = (short)f2bfh(acc[i][j][r] + bv);
                size_t idx = (((size_t)(rowA >> 11) * 8 + (col >> 6)) * 64 + (col & 63)) * 2048
                             + (rowA & 2047);
                *(short4v*)&Vt[idx] = sv;
            } else {
                #pragma unroll
                for (int r = 0; r < 4; ++r)
                    Crm[(size_t)(rowA + r) * 512 + col] = f2bfh(acc[i][j][r] + bv);
            }
        }
    }
}

// ---------------- causal flash attention (swapped-QK, in-register P) ----------------
// Q/K/O: [16384, 512] bf16; Vt: [64 bh][64 d][2048 m] bf16.
// Grid (64 bh, 32 y), qb = 31-y (LPT). Block = one 64-row q-tile, 4 waves x 16 rows.
// QK computed as mfma(K, Q) -> lane holds S^T fragment: q = lane&15, key = n*16+hi*4+r.
// That IS the A-fragment of mfma_16x16x16_bf16 -> PV consumes P from registers (no P LDS).
// m/l/alpha are per-lane scalars (q = lo); alpha/l redistributed to C rows via 4 shfl.
// K/V XOR-swizzled LDS, 32 KB -> 5 blocks/CU.

__device__ __forceinline__ void attn_step(
    int kt, int NT, int qrow, int lo, int hi,
    const short* __restrict__ KsB, const short* __restrict__ VsB,
    short8 (&aq)[2], f32x4 (&o_acc)[4],
    float &m_i, float &l_i)
{
    const int swz = (lo & 7) << 3;

    // QK^T swapped: sa[n] = K_tile(n) * Q^T ; lane: q=lo, key(tile n)=hi*4+r
    f32x4 sa[4] = {};
    #pragma unroll
    for (int s = 0; s < 2; ++s) {
        short8 bk[4];
        #pragma unroll
        for (int n = 0; n < 4; ++n)
            bk[n] = *(const short8*)&KsB[(n * 16 + lo) * 64 + ((s * 32 + hi * 8) ^ swz)];
        #pragma unroll
        for (int n = 0; n < 4; ++n)
            sa[n] = __builtin_amdgcn_mfma_f32_16x16x32_bf16(bk[n], aq[s], sa[n], 0, 0, 0);
    }

    const bool need_mask = (kt == NT - 1);
    const int q = qrow + lo;
    float sv[4][4];
    #pragma unroll
    for (int n = 0; n < 4; ++n)
        #pragma unroll
        for (int r = 0; r < 4; ++r) {
            float x = sa[n][r];
            if (need_mask) {
                int key = kt * 64 + n * 16 + hi * 4 + r;
                if (key > q) x = -1e30f;
            }
            sv[n][r] = x;
        }

    // row max: 15 in-lane + 2 cross-lane (over hi groups)
    float mx0 = fmaxf(fmaxf(sv[0][0], sv[0][1]), fmaxf(sv[0][2], sv[0][3]));
    float mx1 = fmaxf(fmaxf(sv[1][0], sv[1][1]), fmaxf(sv[1][2], sv[1][3]));
    float mx2 = fmaxf(fmaxf(sv[2][0], sv[2][1]), fmaxf(sv[2][2], sv[2][3]));
    float mx3 = fmaxf(fmaxf(sv[3][0], sv[3][1]), fmaxf(sv[3][2], sv[3][3]));
    float mx = fmaxf(fmaxf(mx0, mx1), fmaxf(mx2, mx3));
    mx = fmaxf(mx, __shfl_xor(mx, 16));
    mx = fmaxf(mx, __shfl_xor(mx, 32));
    float mn = fmaxf(m_i, mx);
    float alpha = __expf(m_i - mn);
    m_i = mn;

    #pragma unroll
    for (int n = 0; n < 4; ++n)
        #pragma unroll
        for (int r = 0; r < 4; ++r)
            sv[n][r] = __expf(sv[n][r] - mn);

    // l partial: in-lane sum (cross-lane deferred to epilogue)
    float s0 = (sv[0][0] + sv[0][1]) + (sv[0][2] + sv[0][3]);
    float s1 = (sv[1][0] + sv[1][1]) + (sv[1][2] + sv[1][3]);
    float s2 = (sv[2][0] + sv[2][1]) + (sv[2][2] + sv[2][3]);
    float s3 = (sv[3][0] + sv[3][1]) + (sv[3][2] + sv[3][3]);
    l_i = l_i * alpha + ((s0 + s1) + (s2 + s3));

    // redistribute alpha to this lane's C rows (q = hi*4+r)
    float ar[4];
    #pragma unroll
    for (int r = 0; r < 4; ++r)
        ar[r] = __shfl(alpha, hi * 4 + r);
    #pragma unroll
    for (int t = 0; t < 4; ++t)
        #pragma unroll
        for (int r = 0; r < 4; ++r)
            o_acc[t][r] *= ar[r];

    // pack P in registers: pa[n] = A-frag of 16x16x16 (lane: row=q=lo, k=hi*4+e)
    short4v pa[4];
    #pragma unroll
    for (int n = 0; n < 4; ++n)
        #pragma unroll
        for (int r = 0; r < 4; ++r)
            pa[n][r] = (short)f2bfh(sv[n][r]);

    // PV: o_acc[t] += P(tile n) * V(tile n, d-tile t), K=16 MFMA, B from LDS b64
    #pragma unroll
    for (int n = 0; n < 4; ++n)
        #pragma unroll
        for (int t = 0; t < 4; ++t) {
            short4v vb = *(const short4v*)&VsB[(t * 16 + lo) * 64 + ((n * 16 + hi * 4) ^ swz)];
            o_acc[t] = MFMA_PV(pa[n], vb, o_acc[t]);
        }
}

#define STG_LOAD(kt, KR0, KR1, VR0, VR1) { \
    int rr = tid >> 3, cc = (tid & 7) * 8; \
    KR0 = *(const short8*)&Kp[(rowQ + (size_t)((kt) * 64 + rr)) * 512 + colBase + cc]; \
    KR1 = *(const short8*)&Kp[(rowQ + (size_t)((kt) * 64 + rr + 32)) * 512 + colBase + cc]; \
    VR0 = *(const short8*)&Vh[(size_t)rr * 2048 + (kt) * 64 + cc]; \
    VR1 = *(const short8*)&Vh[(size_t)(rr + 32) * 2048 + (kt) * 64 + cc]; }

#define STG_WRITE(BUF, KR0, KR1, VR0, VR1) { \
    int rr = tid >> 3; \
    int sw = ((tid & 7) * 8) ^ ((rr & 7) << 3); \
    *(short8*)&Ks[BUF][rr * 64 + sw] = KR0; \
    *(short8*)&Ks[BUF][(rr + 32) * 64 + sw] = KR1; \
    *(short8*)&Vs[BUF][rr * 64 + sw] = VR0; \
    *(short8*)&Vs[BUF][(rr + 32) * 64 + sw] = VR1; }

__global__ __launch_bounds__(256, 3) void attn_kernel(
    const unsigned short* __restrict__ Q, const unsigned short* __restrict__ Kp,
    const unsigned short* __restrict__ Vt, unsigned short* __restrict__ O)
{
    const int tid = threadIdx.x, lane = tid & 63, wave = tid >> 6;
    const int lo = lane & 15, hi = lane >> 4;
    const int bh = blockIdx.x;
    const int qb = 31 - blockIdx.y;         // LPT: longest first
    const int bb = bh >> 3, hh = bh & 7;
    const int NT = qb + 1;

    __shared__ __align__(16) short Ks[2][64 * 64];
    __shared__ __align__(16) short Vs[2][64 * 64];

    const size_t rowQ = (size_t)bb * 2048;
    const int colBase = hh * 64;
    const unsigned short* Vh = Vt + (size_t)bh * 64 * 2048;
    const int qrow = qb * 64 + wave * 16;

    short8 aq[2];
    #pragma unroll
    for (int s = 0; s < 2; ++s) {
        aq[s] = *(const short8*)&Q[(rowQ + qrow + lo) * 512 + colBase + s * 32 + hi * 8];
        #pragma unroll
        for (int e = 0; e < 8; ++e)   // fold softmax scale into Q (0.125 exact in bf16)
            aq[s][e] = (short)f2bfh(bf2f((unsigned short)aq[s][e]) * 0.125f);
    }

    f32x4 o_acc[4] = {};
    float m_i = -1e30f, l_i = 0.0f;

    short8 ka0, ka1, va0, va1;
    short8 kb0, kb1, vb0, vb1;

    STG_LOAD(0, ka0, ka1, va0, va1);
    STG_WRITE(0, ka0, ka1, va0, va1);
    if (1 < NT) STG_LOAD(1, kb0, kb1, vb0, vb1);
    __syncthreads();

    for (int kt = 0; kt < NT; ) {
        if (kt + 1 < NT) STG_WRITE(1, kb0, kb1, vb0, vb1);
        if (kt + 2 < NT) STG_LOAD(kt + 2, ka0, ka1, va0, va1);
        attn_step(kt, NT, qrow, lo, hi, Ks[0], Vs[0], aq, o_acc, m_i, l_i);
        __syncthreads();
        ++kt;
        if (kt >= NT) break;
        if (kt + 1 < NT) STG_WRITE(0, ka0, ka1, va0, va1);
        if (kt + 2 < NT) STG_LOAD(kt + 2, kb0, kb1, vb0, vb1);
        attn_step(kt, NT, qrow, lo, hi, Ks[1], Vs[1], aq, o_acc, m_i, l_i);
        __syncthreads();
        ++kt;
    }

    // epilogue: finish l (cross-lane over hi), redistribute to C rows, write O
    float lt = l_i;
    lt += __shfl_xor(lt, 16);
    lt += __shfl_xor(lt, 32);
    float lr[4];
    #pragma unroll
    for (int r = 0; r < 4; ++r)
        lr[r] = __shfl(lt, hi * 4 + r);

    #pragma unroll
    for (int t = 0; t < 4; ++t)
        #pragma unroll
        for (int r = 0; r < 4; ++r) {
            float v = o_acc[t][r] / lr[r];
            O[(rowQ + qrow + hi * 4 + r) * 512 + colBase + t * 16 + lo] = f2bfh(v);
        }
}

extern "C" void kernel_launch(void* const* d_in, const int* in_sizes, int n_in,
                              void* d_out, int out_size, void* d_ws, size_t ws_size,
                              hipStream_t stream)
{
    (void)in_sizes; (void)n_in; (void)out_size; (void)ws_size;
    const float* x   = (const float*)d_in[0];
    const float* w_q = (const float*)d_in[1];
    const float* w_k = (const float*)d_in[2];
    const float* w_v = (const float*)d_in[3];
    const float* ipw = (const float*)d_in[4];
    const float* ipb = (const float*)d_in[5];
    const float* ow  = (const float*)d_in[6];
    const float* ob  = (const float*)d_in[7];

    const int M = 16384;
    const size_t SZ = (size_t)M * 512;
    unsigned short* xb   = (unsigned short*)d_ws;
    unsigned short* wqb  = xb + SZ;
    unsigned short* ipwb = wqb + 786432;
    unsigned short* owb  = ipwb + 786432;
    unsigned short* T    = owb + 262144;
    unsigned short* Kb   = T + (size_t)M * 1536;
    unsigned short* Vt   = Kb + SZ;               // [64 bh][64 d][2048 m]
    float* ct = (float*)(Vt + SZ);
    float* st = ct + 524288;
    unsigned short* Qb   = xb;
    unsigned short* Cb   = T;

    dim3 blk(256);

    // Stage 0: conversions + rope table
    cvt_one<<<dim3((int)(SZ / 8 / 256)), blk, 0, stream>>>(x, xb, (int)(SZ / 8));
    cvt_w<<<dim3(128, 7), blk, 0, stream>>>(w_q, w_k, w_v, ipw, ow, wqb, ipwb, owb);
    rope_table<<<dim3(256), blk, 0, stream>>>(ct, st);

    // Stage 1+2: T[16384,1536] = rope(xb @ [wq;wk;wv]^T)  (fused epilogue)
    gemm_rope<<<dim3(12, 128), blk, 0, stream>>>(xb, wqb, T, ct, st);

    // Stage 3: grouped in_proj (Q,K row-major; V transposed)
    gemm_inproj<<<dim3(4, 128, 3), blk, 0, stream>>>(T, ipwb, ipb, Qb, Kb, Vt);

    // Stage 4: causal flash attention (swapped-QK, LPT, XCD-local per bh)
    attn_kernel<<<dim3(64, 32), blk, 0, stream>>>(Qb, Kb, Vt, Cb);

    // Stage 5: output projection (f32 out)
    gemm_bt<1, 1><<<dim3(4, 128), blk, 0, stream>>>(Cb, 512, owb, ob, (float*)d_out, M, 512, 512);
}